// Round 7
// baseline (466.057 us; speedup 1.0000x reference)
//
#include <hip/hip_runtime.h>
#include <hip/hip_cooperative_groups.h>
#include <cfloat>
#include <cmath>

namespace cg = cooperative_groups;

// PillarEncoder (MI355X / gfx950): out[b][c][y][x] = (4, 64, 496, 432) fp32
#define XL 432
#define YL 496
#define NCH 64
#define HIMG 192
#define WIMG 640
#define HW (HIMG * WIMG)     // 122880
#define PTS_M 32

#define WAVES 16             // 1024 threads/block
#define TPB (WAVES * 64)
#define PPG 4                // pillars per wave-group
#define NBLOCKS 256
#define WPITCH 132           // padded weight row pitch (floats)

typedef const __attribute__((address_space(1))) void* gas_t;
typedef __attribute__((address_space(3))) void* las_t;

__device__ __forceinline__ void gload_lds16(const float* g, float* l) {
    __builtin_amdgcn_global_load_lds((gas_t)g, (las_t)l, 16, 0, 0);
}

#define RED5(v) { v += __shfl_xor(v, 16); v += __shfl_xor(v, 8); v += __shfl_xor(v, 4); \
                  v += __shfl_xor(v, 2);  v += __shfl_xor(v, 1); }

// ============================ shared device pieces ============================

struct ChanConst {
    float As, Bs, Cs, Ds, w07, w18, w4s, w5s, w6s, tch;
    float b1a, b1b, lga, lgb, lba, lbb, gb2;
};

__device__ __forceinline__ ChanConst load_chan_consts(
    int lane, const float* conv_w, const float* bng, const float* bnb,
    const float* bnm, const float* bnv, const float* b1, const float* lng,
    const float* lnb, const float* b2)
{
    ChanConst cc;
    float cw[9];
    #pragma unroll
    for (int i = 0; i < 9; ++i) cw[i] = conv_w[lane * 9 + i];
    const float s = bng[lane] / sqrtf(bnv[lane] + 1e-3f);
    cc.tch = bnb[lane] - bnm[lane] * s;      // BN(0): masked-row value
    cc.As  = (cw[0] + cw[4] + cw[7]) * s;
    cc.Bs  = (cw[1] + cw[5] + cw[8]) * s;
    cc.Cs  = (cw[2] + cw[6]) * s;
    cc.Ds  = cw[3] * s;
    cc.w07 = (cw[0] + cw[7]) * s;
    cc.w18 = (cw[1] + cw[8]) * s;
    cc.w4s = cw[4] * s; cc.w5s = cw[5] * s; cc.w6s = cw[6] * s;
    cc.b1a = b1[lane];  cc.b1b = b1[lane + 64];
    cc.lga = lng[lane]; cc.lgb = lng[lane + 64];
    cc.lba = lnb[lane]; cc.lbb = lnb[lane + 64];
    cc.gb2 = b2[lane];
    return cc;
}

// per-wave pillar-group pipeline body (MODE as in previous rounds)
template<int MODE>
__device__ __forceinline__ void pillar_group(
    int grp, int P, int lane, float* wsw,
    const float* __restrict__ pillars, const int* __restrict__ coors,
    const int* __restrict__ npp, const float* __restrict__ image,
    const float* __restrict__ calibs, const ChanConst& cc,
    const float4* w1rA, const float4* w1rB, const float4* w2r,
    float* __restrict__ feat, int* __restrict__ idxmap, float* __restrict__ out)
{
    const float4* wsf4 = (const float4*)wsw;
    const int pbase = grp * PPG;
    const bool full = (pbase + PPG <= P);

    // ---------- stage 4 pillars' points (2 KB) into ws ----------
    asm volatile("s_waitcnt lgkmcnt(0)" ::: "memory");  // prior LDS reads done
    if (full) {
        const float* src = pillars + (size_t)pbase * (PTS_M * 4);
        gload_lds16(src + lane * 4, wsw);
        gload_lds16(src + 256 + lane * 4, wsw + 256);
    } else {
        #pragma unroll
        for (int h = 0; h < 2; ++h) {
            const int idx = pbase * PTS_M + h * 64 + lane;
            float4 v = make_float4(0.f, 0.f, 0.f, 0.f);
            if (idx < P * PTS_M) v = ((const float4*)pillars)[idx];
            ((float4*)wsw)[h * 64 + lane] = v;
        }
    }

    int bbv[PPG], ixv[PPG], iyv[PPG], nv[PPG];
    #pragma unroll
    for (int pp = 0; pp < PPG; ++pp) {
        const int p = pbase + pp;
        if (p < P) {
            bbv[pp] = coors[p * 3]; ixv[pp] = coors[p * 3 + 1];
            iyv[pp] = coors[p * 3 + 2]; nv[pp] = npp[p];
        } else { bbv[pp] = 0; ixv[pp] = 0; iyv[pp] = 0; nv[pp] = 1; }
    }

    asm volatile("s_waitcnt vmcnt(0) lgkmcnt(0)" ::: "memory");  // points in LDS

    // ---------- means ----------
    const float4 qa = wsf4[lane];
    const float4 qb = wsf4[64 + lane];
    float ax = qa.x, ay = qa.y, az = qa.z;
    float bx = qb.x, by = qb.y, bz = qb.z;
    RED5(ax) RED5(ay) RED5(az)
    RED5(bx) RED5(by) RED5(bz)
    const float axo = __shfl_xor(ax, 32), ayo = __shfl_xor(ay, 32), azo = __shfl_xor(az, 32);
    const float bxo = __shfl_xor(bx, 32), byo = __shfl_xor(by, 32), bzo = __shfl_xor(bz, 32);
    const bool lo = lane < 32;
    float mx[PPG], my[PPG], mz[PPG];
    {
        const float f0 = 1.f / (float)nv[0], f1 = 1.f / (float)nv[1];
        const float f2 = 1.f / (float)nv[2], f3 = 1.f / (float)nv[3];
        mx[0] = (lo ? ax : axo) * f0;  mx[1] = (lo ? axo : ax) * f1;
        my[0] = (lo ? ay : ayo) * f0;  my[1] = (lo ? ayo : ay) * f1;
        mz[0] = (lo ? az : azo) * f0;  mz[1] = (lo ? azo : az) * f1;
        mx[2] = (lo ? bx : bxo) * f2;  mx[3] = (lo ? bxo : bx) * f3;
        my[2] = (lo ? by : byo) * f2;  my[3] = (lo ? byo : by) * f3;
        mz[2] = (lo ? bz : bzo) * f2;  mz[3] = (lo ? bzo : bz) * f3;
    }

    // ---------- projection + image gather + folded bias ----------
    float img[PPG], Es[PPG];
    #pragma unroll
    for (int pp = 0; pp < PPG; ++pp) {
        const float* cb = calibs + bbv[pp] * 12;
        const float pr0 = cb[0]*mx[pp] + cb[1]*my[pp] + cb[2]*mz[pp] + cb[3];
        const float pr1 = cb[4]*mx[pp] + cb[5]*my[pp] + cb[6]*mz[pp] + cb[7];
        const float pr2 = cb[8]*mx[pp] + cb[9]*my[pp] + cb[10]*mz[pp] + cb[11];
        float uf = (pr0 / pr2) * 0.5f;
        float vf = (pr1 / pr2) * 0.5f;
        uf = fminf(fmaxf(uf, 0.f), (float)(WIMG - 1));
        vf = fminf(fmaxf(vf, 0.f), (float)(HIMG - 1));
        const int u = (int)uf, v = (int)vf;
        if (MODE == 2) {
            img[pp] = image[((size_t)bbv[pp] * HW + (size_t)v * WIMG + u) * NCH + lane];
        } else {
            img[pp] = image[(((size_t)(bbv[pp] * NCH + lane)) * HIMG + v) * WIMG + u];
        }
        const float cxp = (float)ixv[pp] * 0.16f + 0.08f;
        const float cyp = (float)iyv[pp] * 0.16f + (-39.6f);
        Es[pp] = cc.tch - (cxp * cc.w07 + cyp * cc.w18 + mx[pp] * cc.w4s + my[pp] * cc.w5s + mz[pp] * cc.w6s);
    }

    // ---------- pooled max ----------
    float pooled[PPG];
    #pragma unroll
    for (int pp = 0; pp < PPG; ++pp) {
        const int n = nv[pp];
        float p0 = (n < PTS_M) ? cc.tch : -FLT_MAX;
        float p1 = -FLT_MAX, p2 = -FLT_MAX, p3 = -FLT_MAX;
        #pragma unroll
        for (int m = 0; m < PTS_M; m += 4) {
            const float4 q0 = wsf4[pp * 32 + m];
            const float4 q1 = wsf4[pp * 32 + m + 1];
            const float4 q2 = wsf4[pp * 32 + m + 2];
            const float4 q3 = wsf4[pp * 32 + m + 3];
            const float h0 = Es[pp] + q0.x*cc.As + q0.y*cc.Bs + q0.z*cc.Cs + q0.w*cc.Ds;
            const float h1 = Es[pp] + q1.x*cc.As + q1.y*cc.Bs + q1.z*cc.Cs + q1.w*cc.Ds;
            const float h2 = Es[pp] + q2.x*cc.As + q2.y*cc.Bs + q2.z*cc.Cs + q2.w*cc.Ds;
            const float h3 = Es[pp] + q3.x*cc.As + q3.y*cc.Bs + q3.z*cc.Cs + q3.w*cc.Ds;
            p0 = fmaxf(p0, (m     < n) ? h0 : -FLT_MAX);
            p1 = fmaxf(p1, (m + 1 < n) ? h1 : -FLT_MAX);
            p2 = fmaxf(p2, (m + 2 < n) ? h2 : -FLT_MAX);
            p3 = fmaxf(p3, (m + 3 < n) ? h3 : -FLT_MAX);
        }
        pooled[pp] = fmaxf(fmaxf(fmaxf(p0, p1), fmaxf(p2, p3)), 0.f);
    }

    // ---------- cat -> ws ----------
    #pragma unroll
    for (int pp = 0; pp < PPG; ++pp) {
        wsw[pp * 128 + lane]      = pooled[pp];
        wsw[pp * 128 + 64 + lane] = img[pp];
    }
    asm volatile("s_waitcnt lgkmcnt(0)" ::: "memory");

    // ---------- GEMM1 ----------
    float accA[PPG], accB[PPG];
    #pragma unroll
    for (int pp = 0; pp < PPG; ++pp) { accA[pp] = cc.b1a; accB[pp] = cc.b1b; }
    #pragma unroll 4
    for (int k4 = 0; k4 < 32; ++k4) {
        const float4 wa = w1rA[k4];
        const float4 wb = w1rB[k4];
        #pragma unroll
        for (int pp = 0; pp < PPG; ++pp) {
            const float4 cv = wsf4[pp * 32 + k4];
            accA[pp] += cv.x*wa.x + cv.y*wa.y + cv.z*wa.z + cv.w*wa.w;
            accB[pp] += cv.x*wb.x + cv.y*wb.y + cv.z*wb.z + cv.w*wb.w;
        }
    }

    // ---------- LayerNorm(128) + relu -> ws ----------
    float sum[PPG], sq[PPG];
    #pragma unroll
    for (int pp = 0; pp < PPG; ++pp) {
        sum[pp] = accA[pp] + accB[pp];
        sq[pp]  = accA[pp]*accA[pp] + accB[pp]*accB[pp];
    }
    #pragma unroll
    for (int d = 32; d; d >>= 1) {
        #pragma unroll
        for (int pp = 0; pp < PPG; ++pp) {
            sum[pp] += __shfl_xor(sum[pp], d);
            sq[pp]  += __shfl_xor(sq[pp], d);
        }
    }
    #pragma unroll
    for (int pp = 0; pp < PPG; ++pp) {
        const float mu  = sum[pp] * (1.f / 128.f);
        const float var = sq[pp] * (1.f / 128.f) - mu * mu;
        const float inv = 1.f / sqrtf(var + 1e-5f);
        const float g0 = (accA[pp] - mu) * inv * cc.lga + cc.lba;
        const float g1 = (accB[pp] - mu) * inv * cc.lgb + cc.lbb;
        wsw[pp * 128 + lane]      = fmaxf(g0, 0.f);
        wsw[pp * 128 + 64 + lane] = fmaxf(g1, 0.f);
    }
    asm volatile("s_waitcnt lgkmcnt(0)" ::: "memory");

    // ---------- GEMM2 + gate + output ----------
    float ac2[PPG];
    #pragma unroll
    for (int pp = 0; pp < PPG; ++pp) ac2[pp] = cc.gb2;
    #pragma unroll 4
    for (int k4 = 0; k4 < 32; ++k4) {
        const float4 w = w2r[k4];
        #pragma unroll
        for (int pp = 0; pp < PPG; ++pp) {
            const float4 gv = wsf4[pp * 32 + k4];
            ac2[pp] += gv.x*w.x + gv.y*w.y + gv.z*w.z + gv.w*w.w;
        }
    }
    #pragma unroll
    for (int pp = 0; pp < PPG; ++pp) {
        const int p = pbase + pp;
        if (p >= P) continue;
        const float gate = 1.f / (1.f + expf(-ac2[pp]));
        const float gf = pooled[pp] * gate + img[pp] * (1.f - gate);
        if (MODE == 0) {
            out[(((bbv[pp] * NCH) + lane) * YL + iyv[pp]) * XL + ixv[pp]] = gf;
        } else {
            feat[(size_t)p * NCH + lane] = gf;
            if (lane == 0)
                idxmap[(bbv[pp] * YL + iyv[pp]) * XL + ixv[pp]] = p + 1;
        }
    }
}

// ============================ MEGA cooperative kernel ============================
// P0 zero idxmap -> P1 transpose image NCHW->NHWC -> gsync -> P2 pillar pipeline
// -> gsync -> P3 canvas stream. One dispatch: full visibility + no launch gaps.
__global__ __launch_bounds__(TPB, 1) void pillar_mega(
    const float* __restrict__ pillars, const int* __restrict__ coors,
    const int* __restrict__ npp, const float* __restrict__ image,
    const float* __restrict__ calibs, const float* __restrict__ conv_w,
    const float* __restrict__ bng, const float* __restrict__ bnb,
    const float* __restrict__ bnm, const float* __restrict__ bnv,
    const float* __restrict__ w1, const float* __restrict__ b1,
    const float* __restrict__ lng, const float* __restrict__ lnb,
    const float* __restrict__ w2, const float* __restrict__ b2,
    float* __restrict__ feat, int* __restrict__ idxmap,
    float* __restrict__ imgT, float* __restrict__ out, int P, int B)
{
    __shared__ float w1p[128 * WPITCH];      // 66 KB (aliased by transpose tile in P1)
    __shared__ float w2p[64 * WPITCH];       // 33 KB
    __shared__ float ws[WAVES][512];         // 32 KB: P2 per-wave scratch; P3 idx row

    cg::grid_group grid = cg::this_grid();
    const int tid  = threadIdx.x;
    const int lane = tid & 63;
    const int wv   = tid >> 6;
    const int bid  = blockIdx.x;

    // ---------------- P0: zero idxmap (int4) ----------------
    {
        const int n4 = (B * YL * XL) / 4;
        int4* o = (int4*)idxmap;
        const int4 z = make_int4(0, 0, 0, 0);
        for (int i = bid * TPB + tid; i < n4; i += NBLOCKS * TPB) o[i] = z;
    }

    // ---------------- P1: transpose image -> imgT (16B/lane both sides) ----------------
    {
        float* tt = w1p;                     // 64*257 floats = 65792 B <= 67584 B
        const int NT = B * (HW / 256);       // tiles of 64c x 256px
        for (int tile = bid; tile < NT; tile += NBLOCKS) {
            const int b   = tile / (HW / 256);
            const int px0 = (tile % (HW / 256)) * 256;
            const float4* base4 = (const float4*)(image + (size_t)b * NCH * HW + px0);
            __syncthreads();                 // prev tile's LDS reads done
            #pragma unroll 2
            for (int i = tid; i < 64 * 64; i += TPB) {    // c x f4
                const int c = i >> 6, f4 = i & 63;
                const float4 v = base4[(size_t)c * (HW / 4) + f4];
                // permuted store: component j of px=4*f4+j at offset f4 + 64*j
                tt[c * 257 + f4]       = v.x;
                tt[c * 257 + f4 + 64]  = v.y;
                tt[c * 257 + f4 + 128] = v.z;
                tt[c * 257 + f4 + 192] = v.w;
            }
            __syncthreads();
            float4* ob4 = (float4*)(imgT + ((size_t)b * HW + px0) * NCH);
            #pragma unroll 2
            for (int i = tid; i < 256 * 16; i += TPB) {   // hw x c4
                const int c4 = i & 15, hw = i >> 4;
                const int off = (hw >> 2) + 64 * (hw & 3);   // o(px) inverse
                float4 o;
                o.x = tt[(4 * c4 + 0) * 257 + off];
                o.y = tt[(4 * c4 + 1) * 257 + off];
                o.z = tt[(4 * c4 + 2) * 257 + off];
                o.w = tt[(4 * c4 + 3) * 257 + off];
                ob4[(size_t)hw * 16 + c4] = o;
            }
        }
    }
    __threadfence();
    grid.sync();

    // ---------------- P2: pillar pipeline (reads imgT, writes feat+idxmap) ----------------
    {
        for (int i = tid; i < 128 * 32; i += TPB) {
            const int j = i >> 5, k4 = i & 31;
            ((float4*)(w1p + j * WPITCH))[k4] = ((const float4*)w1)[i];
        }
        for (int i = tid; i < 64 * 32; i += TPB) {
            const int j = i >> 5, k4 = i & 31;
            ((float4*)(w2p + j * WPITCH))[k4] = ((const float4*)w2)[i];
        }
        __syncthreads();

        const ChanConst cc = load_chan_consts(lane, conv_w, bng, bnb, bnm, bnv, b1, lng, lnb, b2);
        float* wsw = ws[wv];
        const float4* w1rA = (const float4*)(w1p + lane * WPITCH);
        const float4* w1rB = (const float4*)(w1p + (lane + 64) * WPITCH);
        const float4* w2r  = (const float4*)(w2p + lane * WPITCH);

        const int ntasks = (P + PPG - 1) / PPG;
        for (int grp = bid * WAVES + wv; grp < ntasks; grp += NBLOCKS * WAVES)
            pillar_group<2>(grp, P, lane, wsw, pillars, coors, npp, imgT, calibs,
                            cc, w1rA, w1rB, w2r, feat, idxmap, nullptr);
    }
    __threadfence();
    grid.sync();

    // ---------------- P3: canvas stream (full-line stores, fused zero-fill) ----------------
    {
        int* idxrow = (int*)ws;              // 432 ints, per-block
        const int NROW = B * YL;             // 1984
        const int NF4  = XL / 4;             // 108
        for (int by = bid; by < NROW; by += NBLOCKS) {
            const int b = by / YL, y = by % YL;
            __syncthreads();                 // prev row's reads done
            if (tid < 108) ((int4*)idxrow)[tid] = ((const int4*)(idxmap + (size_t)by * XL))[tid];
            __syncthreads();
            float4* orow = (float4*)(out) + (size_t)b * NCH * YL * NF4 + (size_t)y * NF4;
            for (int t = tid; t < NCH * NF4; t += TPB) {
                const int c = t / NF4, x4 = t - c * NF4;
                const int i0 = idxrow[x4*4+0], i1 = idxrow[x4*4+1];
                const int i2 = idxrow[x4*4+2], i3 = idxrow[x4*4+3];
                float4 o = make_float4(0.f, 0.f, 0.f, 0.f);
                if (i0) o.x = feat[(size_t)(i0-1) * NCH + c];
                if (i1) o.y = feat[(size_t)(i1-1) * NCH + c];
                if (i2) o.z = feat[(size_t)(i2-1) * NCH + c];
                if (i3) o.w = feat[(size_t)(i3-1) * NCH + c];
                orow[(size_t)c * YL * NF4 + x4] = o;
            }
        }
    }
}

// ============================ fallback kernels (proven R6 path) ============================

__global__ void zerofill(float4* __restrict__ o, int n4) {
    int i = blockIdx.x * blockDim.x + threadIdx.x;
    const int st = gridDim.x * blockDim.x;
    const float4 z = make_float4(0.f, 0.f, 0.f, 0.f);
    for (; i < n4; i += st) o[i] = z;
}

__global__ __launch_bounds__(256) void transpose_cl(
    const float* __restrict__ img, float* __restrict__ imgT)
{
    __shared__ float t[64 * 257];
    const int b    = blockIdx.x / (HW / 256);
    const int tile = blockIdx.x % (HW / 256);
    const int hw0  = tile * 256;
    const int tid  = threadIdx.x;
    const float* base = img + (size_t)b * NCH * HW + hw0;
    #pragma unroll 4
    for (int c = 0; c < 64; ++c)
        t[c * 257 + tid] = base[(size_t)c * HW + tid];
    __syncthreads();
    float* ob = imgT + ((size_t)b * HW + hw0) * NCH;
    const int c = tid & 63, r = tid >> 6;
    #pragma unroll 4
    for (int it = 0; it < 64; ++it) {
        const int hw = it * 4 + r;
        ob[hw * 64 + c] = t[c * 257 + hw];
    }
}

template<int MODE>
__global__ __launch_bounds__(TPB, 1) void pillar_compute(
    const float* __restrict__ pillars, const int* __restrict__ coors,
    const int* __restrict__ npp, const float* __restrict__ image,
    const float* __restrict__ calibs, const float* __restrict__ conv_w,
    const float* __restrict__ bng, const float* __restrict__ bnb,
    const float* __restrict__ bnm, const float* __restrict__ bnv,
    const float* __restrict__ w1, const float* __restrict__ b1,
    const float* __restrict__ lng, const float* __restrict__ lnb,
    const float* __restrict__ w2, const float* __restrict__ b2,
    float* __restrict__ feat, int* __restrict__ idxmap,
    float* __restrict__ out, int P)
{
    __shared__ float w1p[128 * WPITCH];
    __shared__ float w2p[64 * WPITCH];
    __shared__ float ws[WAVES][512];
    const int tid  = threadIdx.x;
    const int lane = tid & 63;
    const int wv   = tid >> 6;
    for (int i = tid; i < 128 * 32; i += TPB) {
        const int j = i >> 5, k4 = i & 31;
        ((float4*)(w1p + j * WPITCH))[k4] = ((const float4*)w1)[i];
    }
    for (int i = tid; i < 64 * 32; i += TPB) {
        const int j = i >> 5, k4 = i & 31;
        ((float4*)(w2p + j * WPITCH))[k4] = ((const float4*)w2)[i];
    }
    __syncthreads();
    const ChanConst cc = load_chan_consts(lane, conv_w, bng, bnb, bnm, bnv, b1, lng, lnb, b2);
    float* wsw = ws[wv];
    const float4* w1rA = (const float4*)(w1p + lane * WPITCH);
    const float4* w1rB = (const float4*)(w1p + (lane + 64) * WPITCH);
    const float4* w2r  = (const float4*)(w2p + lane * WPITCH);
    const int ntasks = (P + PPG - 1) / PPG;
    for (int grp = blockIdx.x * WAVES + wv; grp < ntasks; grp += NBLOCKS * WAVES)
        pillar_group<MODE>(grp, P, lane, wsw, pillars, coors, npp, image, calibs,
                           cc, w1rA, w1rB, w2r, feat, idxmap, out);
}

__global__ __launch_bounds__(256) void canvas_build(
    const float* __restrict__ feat, const int* __restrict__ idxmap,
    float4* __restrict__ out)
{
    __shared__ int idxrow[XL];
    const int by = blockIdx.x;
    const int b = by / YL, y = by % YL;
    const int* irow = idxmap + (size_t)by * XL;
    for (int i = threadIdx.x; i < XL; i += 256) idxrow[i] = irow[i];
    __syncthreads();
    const int NF4 = XL / 4;
    for (int t = threadIdx.x; t < NCH * NF4; t += 256) {
        const int c = t / NF4, x4 = t - c * NF4;
        const int i0 = idxrow[x4*4+0], i1 = idxrow[x4*4+1];
        const int i2 = idxrow[x4*4+2], i3 = idxrow[x4*4+3];
        float4 o = make_float4(0.f, 0.f, 0.f, 0.f);
        if (i0) o.x = feat[(size_t)(i0-1) * NCH + c];
        if (i1) o.y = feat[(size_t)(i1-1) * NCH + c];
        if (i2) o.z = feat[(size_t)(i2-1) * NCH + c];
        if (i3) o.w = feat[(size_t)(i3-1) * NCH + c];
        out[((size_t)(b * NCH + c) * YL + y) * NF4 + x4] = o;
    }
}

// ============================ host launch ============================

extern "C" void kernel_launch(void* const* d_in, const int* in_sizes, int n_in,
                              void* d_out, int out_size, void* d_ws, size_t ws_size,
                              hipStream_t stream)
{
    const float* pillars = (const float*)d_in[0];
    const int*   coors   = (const int*)d_in[1];
    const int*   npp     = (const int*)d_in[2];
    const float* image   = (const float*)d_in[3];
    const float* calibs  = (const float*)d_in[4];
    const float* conv_w  = (const float*)d_in[6];
    const float* bng     = (const float*)d_in[7];
    const float* bnb     = (const float*)d_in[8];
    const float* bnm     = (const float*)d_in[9];
    const float* bnv     = (const float*)d_in[10];
    const float* w1      = (const float*)d_in[11];
    const float* b1      = (const float*)d_in[12];
    const float* lng     = (const float*)d_in[13];
    const float* lnb     = (const float*)d_in[14];
    const float* w2      = (const float*)d_in[15];
    const float* b2      = (const float*)d_in[16];
    float* out = (float*)d_out;
    const int P = in_sizes[0] / (PTS_M * 4);
    const int B = in_sizes[3] / (NCH * HW);

    const size_t featBytes = (size_t)P * NCH * sizeof(float);        // 10.24 MB
    const size_t idxBytes  = (size_t)B * YL * XL * sizeof(int);      //  3.43 MB
    const size_t imgTBytes = (size_t)B * HW * NCH * sizeof(float);   // 125.8 MB

    if (ws_size >= featBytes + idxBytes + imgTBytes) {
        float* feat   = (float*)d_ws;
        int*   idxmap = (int*)((char*)d_ws + featBytes);
        float* imgT   = (float*)((char*)d_ws + featBytes + idxBytes);

        int Pv = P, Bv = B;
        void* args[] = {
            (void*)&pillars, (void*)&coors, (void*)&npp, (void*)&image,
            (void*)&calibs, (void*)&conv_w, (void*)&bng, (void*)&bnb,
            (void*)&bnm, (void*)&bnv, (void*)&w1, (void*)&b1,
            (void*)&lng, (void*)&lnb, (void*)&w2, (void*)&b2,
            (void*)&feat, (void*)&idxmap, (void*)&imgT, (void*)&out,
            (void*)&Pv, (void*)&Bv
        };
        hipError_t e = hipLaunchCooperativeKernel(
            reinterpret_cast<const void*>(pillar_mega),
            dim3(NBLOCKS), dim3(TPB), args, 0, stream);
        if (e == hipSuccess) return;

        // cooperative rejected -> proven 4-kernel fallback
        zerofill<<<dim3(880), dim3(256), 0, stream>>>((float4*)idxmap, (int)(idxBytes / 16));
        transpose_cl<<<dim3(B * (HW / 256)), dim3(256), 0, stream>>>(image, imgT);
        pillar_compute<2><<<dim3(NBLOCKS), dim3(TPB), 0, stream>>>(
            pillars, coors, npp, imgT, calibs, conv_w, bng, bnb, bnm, bnv,
            w1, b1, lng, lnb, w2, b2, feat, idxmap, nullptr, P);
        canvas_build<<<dim3(B * YL), dim3(256), 0, stream>>>(feat, idxmap, (float4*)d_out);
    } else if (ws_size >= featBytes + idxBytes) {
        float* feat   = (float*)d_ws;
        int*   idxmap = (int*)((char*)d_ws + featBytes);
        zerofill<<<dim3(880), dim3(256), 0, stream>>>((float4*)idxmap, (int)(idxBytes / 16));
        pillar_compute<1><<<dim3(NBLOCKS), dim3(TPB), 0, stream>>>(
            pillars, coors, npp, image, calibs, conv_w, bng, bnb, bnm, bnv,
            w1, b1, lng, lnb, w2, b2, feat, idxmap, nullptr, P);
        canvas_build<<<dim3(B * YL), dim3(256), 0, stream>>>(feat, idxmap, (float4*)d_out);
    } else {
        zerofill<<<dim3(2048), dim3(256), 0, stream>>>((float4*)d_out, out_size / 4);
        pillar_compute<0><<<dim3(NBLOCKS), dim3(TPB), 0, stream>>>(
            pillars, coors, npp, image, calibs, conv_w, bng, bnb, bnm, bnv,
            w1, b1, lng, lnb, w2, b2, nullptr, nullptr, out, P);
    }
}